// Round 8
// baseline (81.939 us; speedup 1.0000x reference)
//
#include <hip/hip_runtime.h>

#define L 512
#define LMASK 511
#define HID 32

constexpr int THREADS        = 256;
constexpr int ROWS_PER_BLOCK = 4;
constexpr int BLOCKS_PER_B   = L / ROWS_PER_BLOCK;   // 128
constexpr int NTAB           = 2048;                 // cells of 1/64 z', z' in [-16,16]
constexpr int GT             = 5;                    // table groups (20 h)
constexpr int NPAIR_E        = 6;                    // exp pairs (12 h)

// Magic addressing: mantissa of (256*z' + 4098 + 2^23) = byte offset into table
constexpr float MAGIC   = 8388608.0f;                // 2^23
constexpr float CLAMPLO = 8388608.0f;                // cell 0
constexpr float CLAMPHI = 8396796.0f;                // 2^23 + 4*2047

// Fused: per-block prep + table build + stencil + hybrid table/exp2 MLP.
// R8 DIAGNOSTIC: adds a dummy double-pass gather loop on a replica table
// (kept alive via asm, never stored) to force site_kernel into the rocprof
// top-5 and expose VALUBusy / SQ_LDS_BANK_CONFLICT / Occupancy.
__global__ __launch_bounds__(THREADS)
void site_kernel(const float* __restrict__ x,
                 const float* __restrict__ W1,
                 const float* __restrict__ b1,
                 const float* __restrict__ W2,
                 float* __restrict__ partial) {
    __shared__ __align__(16) float tab_s[NTAB];      // T(z')=1/(1+2^z'), nearest
    __shared__ __align__(16) float tab2_s[NTAB];     // replica for dummy gathers
    __shared__ __align__(16) float zw_s[GT * 16];    // table groups {wa4 wb4 wc4 w04}
    __shared__ __align__(16) float w2t_s[GT * 4];    // table-path w2
    __shared__ __align__(16) float ew_s[NPAIR_E * 8];// exp pairs {wa01 wb01 wc01 w001}
    __shared__ __align__(8)  float ew2_s[NPAIR_E * 2];

    const int t = threadIdx.x;
    const float Ke = 2.8853900817779268f;            // 2*log2(e)

    if (t < HID) {
        if (t < 4 * GT) {                            // table-path h
            const float K256 = 256.0f * Ke;
            const int g = t >> 2, q = t & 3;
            zw_s[g * 16 +  0 + q] = K256 * W1[t * 3 + 0];
            zw_s[g * 16 +  4 + q] = K256 * W1[t * 3 + 1];
            zw_s[g * 16 +  8 + q] = K256 * W1[t * 3 + 2];
            zw_s[g * 16 + 12 + q] = fmaf(K256, b1[t], 4098.0f + MAGIC);
            w2t_s[t] = -2.0f * W2[t];                // tanh = 1 - 2*T
        } else {                                     // exp-path h
            const int e = t - 4 * GT, p = e >> 1, q = e & 1;
            ew_s[p * 8 + 0 + q] = Ke * W1[t * 3 + 0];
            ew_s[p * 8 + 2 + q] = Ke * W1[t * 3 + 1];
            ew_s[p * 8 + 4 + q] = Ke * W1[t * 3 + 2];
            ew_s[p * 8 + 6 + q] = Ke * b1[t];
            ew2_s[p * 2 + q]    = -2.0f * W2[t];
        }
    }
    // Table entry i: T at the true center of cell i (see magic mapping).
    for (int i = t; i < NTAB; i += THREADS) {
        const float zp = fmaf((float)i, 0.015625f, -16.001953125f);
        const float v  = __builtin_amdgcn_rcpf(1.0f + __builtin_amdgcn_exp2f(zp));
        tab_s[i]  = v;
        tab2_s[i] = v;
    }
    __syncthreads();

    const int blk = blockIdx.x;
    const int b   = blk >> 7;                        // / BLOCKS_PER_B
    const int i0  = (blk & (BLOCKS_PER_B - 1)) * ROWS_PER_BLOCK;
    const float* __restrict__ xb = x + (size_t)b * (L * L);

    // Features for 8 sites: rows i0..i0+3, cols t and t+256.
    float F0[8], F1[8], F2[8];
#pragma unroll
    for (int g = 0; g < 2; ++g) {
        const int j  = t + g * THREADS;
        const int jm = (j + LMASK) & LMASK, jp = (j + 1) & LMASK;

        float cc[6];                                 // center col, rows i0-1..i0+4
#pragma unroll
        for (int r = 0; r < 6; ++r) {
            const int i = (i0 + r - 1 + L) & LMASK;
            cc[r] = xb[i * L + j];
        }
#pragma unroll
        for (int s = 0; s < 4; ++s) {
            const int i   = i0 + s;
            const float lf = xb[i * L + jm];
            const float rg = xb[i * L + jp];
            const float c  = cc[s + 1];
            const float lr = lf + rg;                // == sx
            const float x1 = lr + cc[s] + cc[s + 2];
            const int k = g * 4 + s;
            F0[k] = c * c;  F1[k] = x1 * c;  F2[k] = lr * c;
        }
    }

    float acc[8] = {0.f, 0.f, 0.f, 0.f, 0.f, 0.f, 0.f, 0.f};
    const char* __restrict__ tb  = (const char*)tab_s;
    const char* __restrict__ tb2 = (const char*)tab2_s;

    // ---- Table path: 20 hidden units (LDS-gather pipe) ----
#pragma unroll 1
    for (int gq = 0; gq < GT; ++gq) {
        const float4 wa  = *(const float4*)&zw_s[gq * 16 + 0];
        const float4 wb  = *(const float4*)&zw_s[gq * 16 + 4];
        const float4 wc  = *(const float4*)&zw_s[gq * 16 + 8];
        const float4 w0  = *(const float4*)&zw_s[gq * 16 + 12];
        const float4 w2v = *(const float4*)&w2t_s[gq * 4];
#pragma unroll
        for (int q = 0; q < 4; ++q) {
            const float waq = ((const float*)&wa)[q];
            const float wbq = ((const float*)&wb)[q];
            const float wcq = ((const float*)&wc)[q];
            const float w0q = ((const float*)&w0)[q];
            const float w2q = ((const float*)&w2v)[q];
#pragma unroll
            for (int s = 0; s < 8; ++s) {
                const float uu = fmaf(F0[s], waq, fmaf(F1[s], wbq, fmaf(F2[s], wcq, w0q)));
                const float uc = __builtin_amdgcn_fmed3f(uu, CLAMPLO, CLAMPHI);
                const int  off = __float_as_int(uc) & 0x007FFFFC;
                const float y  = *reinterpret_cast<const float*>(tb + off);
                acc[s] = fmaf(w2q, y, acc[s]);
            }
        }
    }

    // ---- DIAGNOSTIC dummy gather load: 2 passes x 8 groups x 8 sites ----
    // Reads the replica table (no CSE with the real loop), result kept alive
    // via asm and never stored -> output unchanged.
    float dacc0 = 0.f, dacc1 = 0.f;
#pragma unroll 1
    for (int pass = 0; pass < 2; ++pass) {
        const int xr = pass * 4;                     // defeat cross-pass CSE
#pragma unroll 1
        for (int gq = 0; gq < 8; ++gq) {
            const int gm = (gq >= GT) ? gq - GT : gq;
            const float4 wa  = *(const float4*)&zw_s[gm * 16 + 0];
            const float4 wb  = *(const float4*)&zw_s[gm * 16 + 4];
            const float4 wc  = *(const float4*)&zw_s[gm * 16 + 8];
            const float4 w0  = *(const float4*)&zw_s[gm * 16 + 12];
#pragma unroll
            for (int q = 0; q < 4; ++q) {
                const float waq = ((const float*)&wa)[q];
                const float wbq = ((const float*)&wb)[q];
                const float wcq = ((const float*)&wc)[q];
                const float w0q = ((const float*)&w0)[q];
#pragma unroll
                for (int s = 0; s < 8; ++s) {
                    const float uu = fmaf(F0[s], waq, fmaf(F1[s], wbq, fmaf(F2[s], wcq, w0q)));
                    const float uc = __builtin_amdgcn_fmed3f(uu, CLAMPLO, CLAMPHI);
                    const int  off = (__float_as_int(uc) & 0x007FFFFC) ^ xr;
                    const float y  = *reinterpret_cast<const float*>(tb2 + off);
                    if (s & 1) dacc1 = fmaf(0.5f, y, dacc1);
                    else       dacc0 = fmaf(0.5f, y, dacc0);
                }
            }
        }
    }
    asm volatile("" : : "v"(dacc0), "v"(dacc1));     // keep dummy work live

    // ---- Exp path: 12 hidden units in 6 pairs (VALU + trans pipes) ----
#pragma unroll 1
    for (int p = 0; p < NPAIR_E; ++p) {
        const float4 e0 = *(const float4*)&ew_s[p * 8 + 0];  // wa0 wa1 wb0 wb1
        const float4 e1 = *(const float4*)&ew_s[p * 8 + 4];  // wc0 wc1 w00 w01
        const float2 w2p = *(const float2*)&ew2_s[p * 2];
        const float wa0 = e0.x, wa1 = e0.y, wb0 = e0.z, wb1 = e0.w;
        const float wc0 = e1.x, wc1 = e1.y, w00 = e1.z, w01 = e1.w;
#pragma unroll
        for (int s = 0; s < 8; ++s) {
            float z0 = fmaf(F0[s], wa0, fmaf(F1[s], wb0, fmaf(F2[s], wc0, w00)));
            float z1 = fmaf(F0[s], wa1, fmaf(F1[s], wb1, fmaf(F2[s], wc1, w01)));
            z0 = __builtin_amdgcn_fmed3f(z0, -30.0f, 30.0f);
            z1 = __builtin_amdgcn_fmed3f(z1, -30.0f, 30.0f);
            const float d0 = 1.0f + __builtin_amdgcn_exp2f(z0);
            const float d1 = 1.0f + __builtin_amdgcn_exp2f(z1);
            const float nm = fmaf(w2p.x, d1, w2p.y * d0); // w2a/d0+w2b/d1
            const float rr = __builtin_amdgcn_rcpf(d0 * d1);
            acc[s] = fmaf(nm, rr, acc[s]);
        }
    }

    float a = ((acc[0] + acc[1]) + (acc[2] + acc[3]))
            + ((acc[4] + acc[5]) + (acc[6] + acc[7]));
#pragma unroll
    for (int off = 32; off > 0; off >>= 1)
        a += __shfl_down(a, off, 64);

    __shared__ float wsum[THREADS / 64];
    const int wid = t >> 6, lane = t & 63;
    if (lane == 0) wsum[wid] = a;
    __syncthreads();
    if (t == 0)
        partial[blk] = (wsum[0] + wsum[1]) + (wsum[2] + wsum[3]);
}

// Deterministic fixed-order reduction + folded tanh constant.
__global__ __launch_bounds__(128)
void reduce_kernel(const float* __restrict__ partial,
                   const float* __restrict__ W2,
                   const float* __restrict__ b2,
                   float* __restrict__ out) {
    const int b = blockIdx.x, t = threadIdx.x;
    const float NS = (float)(L * L);                 // 262144 sites per config

    float v = partial[b * BLOCKS_PER_B + t];
    if (t < HID) v += NS * W2[t];                    // + L^2 * sum_h W2[h]
    if (t == 0)  v += NS * b2[0];                    // + L^2 * b2

#pragma unroll
    for (int off = 32; off > 0; off >>= 1)
        v += __shfl_down(v, off, 64);

    __shared__ float ws2[2];
    if ((t & 63) == 0) ws2[t >> 6] = v;
    __syncthreads();
    if (t == 0) out[b] = ws2[0] + ws2[1];
}

extern "C" void kernel_launch(void* const* d_in, const int* in_sizes, int n_in,
                              void* d_out, int out_size, void* d_ws, size_t ws_size,
                              hipStream_t stream) {
    const float* x  = (const float*)d_in[0];
    const float* W1 = (const float*)d_in[1];
    const float* b1 = (const float*)d_in[2];
    const float* W2 = (const float*)d_in[3];
    const float* b2 = (const float*)d_in[4];
    float* out      = (float*)d_out;
    float* partial  = (float*)d_ws;                  // 2048 floats

    const int B = in_sizes[0] / (L * L);             // 16

    site_kernel<<<B * BLOCKS_PER_B, THREADS, 0, stream>>>(x, W1, b1, W2, partial);
    reduce_kernel<<<B, 128, 0, stream>>>(partial, W2, b2, out);
}

// Round 9
// 39.851 us; speedup vs baseline: 2.0561x; 2.0561x over previous
//
#include <hip/hip_runtime.h>

#define L 512
#define LMASK 511
#define HID 32

constexpr int THREADS        = 256;
constexpr int ROWS_PER_BLOCK = 4;
constexpr int BLOCKS_PER_B   = L / ROWS_PER_BLOCK;   // 128
constexpr int NTAB           = 2048;                 // cells of 1/64 z', z' in [-16,16]
constexpr int GT             = 5;                    // table groups (20 h)
constexpr int NPAIR_E        = 6;                    // exp pairs (12 h)

// Magic addressing: mantissa of (256*z' + 4098 + 2^23) = byte offset into table
constexpr float MAGIC   = 8388608.0f;                // 2^23
constexpr float CLAMPLO = 8388608.0f;                // cell 0
constexpr float CLAMPHI = 8396796.0f;                // 2^23 + 4*2047

// d_ws float layout: [0,2048) partials | [2048,2208) packed weights:
//   +0   : zw   (5 groups x 16: wa4 wb4 wc4 w04)   80
//   +80  : w2t  (20)
//   +100 : ew   (6 pairs x 8: wa01 wb01 wc01 w001) 48
//   +148 : ew2  (12)
#define WGT_OFF 2048

__global__ __launch_bounds__(64)
void prep_kernel(const float* __restrict__ W1, const float* __restrict__ b1,
                 const float* __restrict__ W2, float* __restrict__ wg) {
    const int t = threadIdx.x;
    const float Ke = 2.8853900817779268f;            // 2*log2(e)
    if (t < 4 * GT) {                                // table-path h
        const float K256 = 256.0f * Ke;
        const int g = t >> 2, q = t & 3;
        wg[g * 16 +  0 + q] = K256 * W1[t * 3 + 0];
        wg[g * 16 +  4 + q] = K256 * W1[t * 3 + 1];
        wg[g * 16 +  8 + q] = K256 * W1[t * 3 + 2];
        wg[g * 16 + 12 + q] = fmaf(K256, b1[t], 4098.0f + MAGIC);
        wg[80 + t] = -2.0f * W2[t];                  // tanh = 1 - 2*T
    } else if (t < HID) {                            // exp-path h
        const int e = t - 4 * GT, p = e >> 1, q = e & 1;
        wg[100 + p * 8 + 0 + q] = Ke * W1[t * 3 + 0];
        wg[100 + p * 8 + 2 + q] = Ke * W1[t * 3 + 1];
        wg[100 + p * 8 + 4 + q] = Ke * W1[t * 3 + 2];
        wg[100 + p * 8 + 6 + q] = Ke * b1[t];
        wg[148 + p * 2 + q]     = -2.0f * W2[t];
    }
}

__global__ __launch_bounds__(THREADS)
void site_kernel(const float* __restrict__ x, const float* __restrict__ wg,
                 float* __restrict__ partial) {
    __shared__ __align__(16) float tab_s[NTAB];      // T(z')=1/(1+2^z'), nearest

    const int t = threadIdx.x;
    // Table entry i: T at the true center of cell i (magic mapping).
    for (int i = t; i < NTAB; i += THREADS) {
        const float zp = fmaf((float)i, 0.015625f, -16.001953125f);
        tab_s[i] = __builtin_amdgcn_rcpf(1.0f + __builtin_amdgcn_exp2f(zp));
    }
    __syncthreads();

    const int blk = blockIdx.x;
    const int b   = blk >> 7;                        // / BLOCKS_PER_B
    const int i0  = (blk & (BLOCKS_PER_B - 1)) * ROWS_PER_BLOCK;
    const float* __restrict__ xb = x + (size_t)b * (L * L);

    // Features for 8 sites: rows i0..i0+3, cols t and t+256.
    float F0[8], F1[8], F2[8];
#pragma unroll
    for (int g = 0; g < 2; ++g) {
        const int j  = t + g * THREADS;
        const int jm = (j + LMASK) & LMASK, jp = (j + 1) & LMASK;

        float cc[6];                                 // center col, rows i0-1..i0+4
#pragma unroll
        for (int r = 0; r < 6; ++r) {
            const int i = (i0 + r - 1 + L) & LMASK;
            cc[r] = xb[i * L + j];
        }
#pragma unroll
        for (int s = 0; s < 4; ++s) {
            const int i   = i0 + s;
            const float lf = xb[i * L + jm];
            const float rg = xb[i * L + jp];
            const float c  = cc[s + 1];
            const float lr = lf + rg;                // == sx
            const float x1 = lr + cc[s] + cc[s + 2];
            const int k = g * 4 + s;
            F0[k] = c * c;  F1[k] = x1 * c;  F2[k] = lr * c;
        }
    }

    float acc[8] = {0.f, 0.f, 0.f, 0.f, 0.f, 0.f, 0.f, 0.f};
    const char* __restrict__ tb = (const char*)tab_s;

    // One table group (4 h x 8 sites): LDS-gather pipe.
    auto tgroup = [&](const int g) {
#pragma unroll
        for (int q = 0; q < 4; ++q) {
            const float waq = wg[g * 16 +  0 + q];   // uniform -> s_load
            const float wbq = wg[g * 16 +  4 + q];
            const float wcq = wg[g * 16 +  8 + q];
            const float w0q = wg[g * 16 + 12 + q];
            const float w2q = wg[80 + g * 4 + q];
#pragma unroll
            for (int s = 0; s < 8; ++s) {
                const float uu = fmaf(F0[s], waq, fmaf(F1[s], wbq, fmaf(F2[s], wcq, w0q)));
                const float uc = __builtin_amdgcn_fmed3f(uu, CLAMPLO, CLAMPHI);
                const int  off = __float_as_int(uc) & 0x007FFFFC;
                const float y  = *reinterpret_cast<const float*>(tb + off);
                acc[s] = fmaf(w2q, y, acc[s]);
            }
        }
    };
    // One exp pair (2 h x 8 sites): issue-port (VALU+trans) work.
    auto epair = [&](const int p) {
        const float wa0 = wg[100 + p * 8 + 0], wa1 = wg[100 + p * 8 + 1];
        const float wb0 = wg[100 + p * 8 + 2], wb1 = wg[100 + p * 8 + 3];
        const float wc0 = wg[100 + p * 8 + 4], wc1 = wg[100 + p * 8 + 5];
        const float w00 = wg[100 + p * 8 + 6], w01 = wg[100 + p * 8 + 7];
        const float w2x = wg[148 + p * 2 + 0], w2y = wg[148 + p * 2 + 1];
#pragma unroll
        for (int s = 0; s < 8; ++s) {
            float z0 = fmaf(F0[s], wa0, fmaf(F1[s], wb0, fmaf(F2[s], wc0, w00)));
            float z1 = fmaf(F0[s], wa1, fmaf(F1[s], wb1, fmaf(F2[s], wc1, w01)));
            z0 = __builtin_amdgcn_fmed3f(z0, -30.0f, 30.0f);
            z1 = __builtin_amdgcn_fmed3f(z1, -30.0f, 30.0f);
            const float d0 = 1.0f + __builtin_amdgcn_exp2f(z0);
            const float d1 = 1.0f + __builtin_amdgcn_exp2f(z1);
            const float nm = fmaf(w2x, d1, w2y * d0);     // w2a/d0 + w2b/d1
            const float rr = __builtin_amdgcn_rcpf(d0 * d1);
            acc[s] = fmaf(nm, rr, acc[s]);
        }
    };

    // Interleaved straight-line schedule: LDS gathers overlap exp issue work.
    tgroup(0); epair(0);
    tgroup(1); epair(1);
    tgroup(2); epair(2);
    tgroup(3); epair(3);
    tgroup(4); epair(4); epair(5);

    float a = ((acc[0] + acc[1]) + (acc[2] + acc[3]))
            + ((acc[4] + acc[5]) + (acc[6] + acc[7]));
#pragma unroll
    for (int off = 32; off > 0; off >>= 1)
        a += __shfl_down(a, off, 64);

    __shared__ float wsum[THREADS / 64];
    const int wid = t >> 6, lane = t & 63;
    if (lane == 0) wsum[wid] = a;
    __syncthreads();
    if (t == 0)
        partial[blk] = (wsum[0] + wsum[1]) + (wsum[2] + wsum[3]);
}

// Deterministic fixed-order reduction + folded tanh constant.
__global__ __launch_bounds__(128)
void reduce_kernel(const float* __restrict__ partial,
                   const float* __restrict__ W2,
                   const float* __restrict__ b2,
                   float* __restrict__ out) {
    const int b = blockIdx.x, t = threadIdx.x;
    const float NS = (float)(L * L);                 // 262144 sites per config

    float v = partial[b * BLOCKS_PER_B + t];
    if (t < HID) v += NS * W2[t];                    // + L^2 * sum_h W2[h]
    if (t == 0)  v += NS * b2[0];                    // + L^2 * b2

#pragma unroll
    for (int off = 32; off > 0; off >>= 1)
        v += __shfl_down(v, off, 64);

    __shared__ float ws2[2];
    if ((t & 63) == 0) ws2[t >> 6] = v;
    __syncthreads();
    if (t == 0) out[b] = ws2[0] + ws2[1];
}

extern "C" void kernel_launch(void* const* d_in, const int* in_sizes, int n_in,
                              void* d_out, int out_size, void* d_ws, size_t ws_size,
                              hipStream_t stream) {
    const float* x  = (const float*)d_in[0];
    const float* W1 = (const float*)d_in[1];
    const float* b1 = (const float*)d_in[2];
    const float* W2 = (const float*)d_in[3];
    const float* b2 = (const float*)d_in[4];
    float* out      = (float*)d_out;
    float* partial  = (float*)d_ws;                  // 2048 floats
    float* wg       = (float*)d_ws + WGT_OFF;        // 160 floats

    const int B = in_sizes[0] / (L * L);             // 16

    prep_kernel<<<1, 64, 0, stream>>>(W1, b1, W2, wg);
    site_kernel<<<B * BLOCKS_PER_B, THREADS, 0, stream>>>(x, wg, partial);
    reduce_kernel<<<B, 128, 0, stream>>>(partial, W2, b2, out);
}

// Round 10
// 32.980 us; speedup vs baseline: 2.4845x; 1.2084x over previous
//
#include <hip/hip_runtime.h>

#define L 512
#define LMASK 511
#define HID 32

constexpr int THREADS        = 256;
constexpr int ROWS_PER_BLOCK = 4;
constexpr int BLOCKS_PER_B   = L / ROWS_PER_BLOCK;   // 128
constexpr int NTAB           = 2048;                 // cells of 1/64 z', z' in [-16,16]
constexpr int GT             = 5;                    // table groups (20 h)
constexpr int NPAIR_E        = 6;                    // exp pairs (12 h)

// Magic addressing: mantissa of (256*z' + 4098 + 2^23) = byte offset into table
constexpr float MAGIC   = 8388608.0f;                // 2^23
constexpr float CLAMPLO = 8388608.0f;                // cell 0
constexpr float CLAMPHI = 8396796.0f;                // 2^23 + 4*2047

// Fused: per-block prep + table build + stencil + hybrid table/exp2 MLP.
// R10: wave-parity phase stagger — odd waves run the exp phase first so the
// LDS-gather pipe and the VALU/trans issue port are occupied concurrently
// by different waves (breaks the phase-aligned convoy seen through R7).
__global__ __launch_bounds__(THREADS)
void site_kernel(const float* __restrict__ x,
                 const float* __restrict__ W1,
                 const float* __restrict__ b1,
                 const float* __restrict__ W2,
                 float* __restrict__ partial) {
    __shared__ __align__(16) float tab_s[NTAB];      // T(z')=1/(1+2^z'), nearest
    __shared__ __align__(16) float zw_s[GT * 16];    // table groups {wa4 wb4 wc4 w04}
    __shared__ __align__(16) float w2t_s[GT * 4];    // table-path w2
    __shared__ __align__(16) float ew_s[NPAIR_E * 8];// exp pairs {wa01 wb01 wc01 w001}
    __shared__ __align__(8)  float ew2_s[NPAIR_E * 2];

    const int t = threadIdx.x;
    const float Ke = 2.8853900817779268f;            // 2*log2(e)

    if (t < HID) {
        if (t < 4 * GT) {                            // table-path h
            const float K256 = 256.0f * Ke;
            const int g = t >> 2, q = t & 3;
            zw_s[g * 16 +  0 + q] = K256 * W1[t * 3 + 0];
            zw_s[g * 16 +  4 + q] = K256 * W1[t * 3 + 1];
            zw_s[g * 16 +  8 + q] = K256 * W1[t * 3 + 2];
            zw_s[g * 16 + 12 + q] = fmaf(K256, b1[t], 4098.0f + MAGIC);
            w2t_s[t] = -2.0f * W2[t];                // tanh = 1 - 2*T
        } else {                                     // exp-path h
            const int e = t - 4 * GT, p = e >> 1, q = e & 1;
            ew_s[p * 8 + 0 + q] = Ke * W1[t * 3 + 0];
            ew_s[p * 8 + 2 + q] = Ke * W1[t * 3 + 1];
            ew_s[p * 8 + 4 + q] = Ke * W1[t * 3 + 2];
            ew_s[p * 8 + 6 + q] = Ke * b1[t];
            ew2_s[p * 2 + q]    = -2.0f * W2[t];
        }
    }
    // Table entry i: T at the true center of cell i (magic mapping).
    for (int i = t; i < NTAB; i += THREADS) {
        const float zp = fmaf((float)i, 0.015625f, -16.001953125f);
        tab_s[i] = __builtin_amdgcn_rcpf(1.0f + __builtin_amdgcn_exp2f(zp));
    }
    __syncthreads();

    const int blk = blockIdx.x;
    const int b   = blk >> 7;                        // / BLOCKS_PER_B
    const int i0  = (blk & (BLOCKS_PER_B - 1)) * ROWS_PER_BLOCK;
    const float* __restrict__ xb = x + (size_t)b * (L * L);

    // Features for 8 sites: rows i0..i0+3, cols t and t+256.
    float F0[8], F1[8], F2[8];
#pragma unroll
    for (int g = 0; g < 2; ++g) {
        const int j  = t + g * THREADS;
        const int jm = (j + LMASK) & LMASK, jp = (j + 1) & LMASK;

        float cc[6];                                 // center col, rows i0-1..i0+4
#pragma unroll
        for (int r = 0; r < 6; ++r) {
            const int i = (i0 + r - 1 + L) & LMASK;
            cc[r] = xb[i * L + j];
        }
#pragma unroll
        for (int s = 0; s < 4; ++s) {
            const int i   = i0 + s;
            const float lf = xb[i * L + jm];
            const float rg = xb[i * L + jp];
            const float c  = cc[s + 1];
            const float lr = lf + rg;                // == sx
            const float x1 = lr + cc[s] + cc[s + 2];
            const int k = g * 4 + s;
            F0[k] = c * c;  F1[k] = x1 * c;  F2[k] = lr * c;
        }
    }

    float acc[8] = {0.f, 0.f, 0.f, 0.f, 0.f, 0.f, 0.f, 0.f};
    const char* __restrict__ tb = (const char*)tab_s;

    // ---- Table phase: 20 hidden units (LDS-gather pipe) ----
    auto table_all = [&]() {
#pragma unroll 1
        for (int gq = 0; gq < GT; ++gq) {
            const float4 wa  = *(const float4*)&zw_s[gq * 16 + 0];
            const float4 wb  = *(const float4*)&zw_s[gq * 16 + 4];
            const float4 wc  = *(const float4*)&zw_s[gq * 16 + 8];
            const float4 w0  = *(const float4*)&zw_s[gq * 16 + 12];
            const float4 w2v = *(const float4*)&w2t_s[gq * 4];
#pragma unroll
            for (int q = 0; q < 4; ++q) {
                const float waq = ((const float*)&wa)[q];
                const float wbq = ((const float*)&wb)[q];
                const float wcq = ((const float*)&wc)[q];
                const float w0q = ((const float*)&w0)[q];
                const float w2q = ((const float*)&w2v)[q];
#pragma unroll
                for (int s = 0; s < 8; ++s) {
                    const float uu = fmaf(F0[s], waq, fmaf(F1[s], wbq, fmaf(F2[s], wcq, w0q)));
                    const float uc = __builtin_amdgcn_fmed3f(uu, CLAMPLO, CLAMPHI);
                    const int  off = __float_as_int(uc) & 0x007FFFFC;
                    const float y  = *reinterpret_cast<const float*>(tb + off);
                    acc[s] = fmaf(w2q, y, acc[s]);
                }
            }
        }
    };
    // ---- Exp phase: 12 hidden units in 6 pairs (VALU + trans issue port) ----
    auto exp_all = [&]() {
#pragma unroll 1
        for (int p = 0; p < NPAIR_E; ++p) {
            const float4 e0 = *(const float4*)&ew_s[p * 8 + 0];  // wa0 wa1 wb0 wb1
            const float4 e1 = *(const float4*)&ew_s[p * 8 + 4];  // wc0 wc1 w00 w01
            const float2 w2p = *(const float2*)&ew2_s[p * 2];
            const float wa0 = e0.x, wa1 = e0.y, wb0 = e0.z, wb1 = e0.w;
            const float wc0 = e1.x, wc1 = e1.y, w00 = e1.z, w01 = e1.w;
#pragma unroll
            for (int s = 0; s < 8; ++s) {
                float z0 = fmaf(F0[s], wa0, fmaf(F1[s], wb0, fmaf(F2[s], wc0, w00)));
                float z1 = fmaf(F0[s], wa1, fmaf(F1[s], wb1, fmaf(F2[s], wc1, w01)));
                z0 = __builtin_amdgcn_fmed3f(z0, -30.0f, 30.0f);
                z1 = __builtin_amdgcn_fmed3f(z1, -30.0f, 30.0f);
                const float d0 = 1.0f + __builtin_amdgcn_exp2f(z0);
                const float d1 = 1.0f + __builtin_amdgcn_exp2f(z1);
                const float nm = fmaf(w2p.x, d1, w2p.y * d0); // w2a/d0+w2b/d1
                const float rr = __builtin_amdgcn_rcpf(d0 * d1);
                acc[s] = fmaf(nm, rr, acc[s]);
            }
        }
    };

    // Wave-parity stagger: odd waves exp-first, even waves table-first.
    if ((t >> 6) & 1) { exp_all(); table_all(); }
    else              { table_all(); exp_all(); }

    float a = ((acc[0] + acc[1]) + (acc[2] + acc[3]))
            + ((acc[4] + acc[5]) + (acc[6] + acc[7]));
#pragma unroll
    for (int off = 32; off > 0; off >>= 1)
        a += __shfl_down(a, off, 64);

    __shared__ float wsum[THREADS / 64];
    const int wid = t >> 6, lane = t & 63;
    if (lane == 0) wsum[wid] = a;
    __syncthreads();
    if (t == 0)
        partial[blk] = (wsum[0] + wsum[1]) + (wsum[2] + wsum[3]);
}

// Deterministic fixed-order reduction + folded tanh constant.
__global__ __launch_bounds__(128)
void reduce_kernel(const float* __restrict__ partial,
                   const float* __restrict__ W2,
                   const float* __restrict__ b2,
                   float* __restrict__ out) {
    const int b = blockIdx.x, t = threadIdx.x;
    const float NS = (float)(L * L);                 // 262144 sites per config

    float v = partial[b * BLOCKS_PER_B + t];
    if (t < HID) v += NS * W2[t];                    // + L^2 * sum_h W2[h]
    if (t == 0)  v += NS * b2[0];                    // + L^2 * b2

#pragma unroll
    for (int off = 32; off > 0; off >>= 1)
        v += __shfl_down(v, off, 64);

    __shared__ float ws2[2];
    if ((t & 63) == 0) ws2[t >> 6] = v;
    __syncthreads();
    if (t == 0) out[b] = ws2[0] + ws2[1];
}

extern "C" void kernel_launch(void* const* d_in, const int* in_sizes, int n_in,
                              void* d_out, int out_size, void* d_ws, size_t ws_size,
                              hipStream_t stream) {
    const float* x  = (const float*)d_in[0];
    const float* W1 = (const float*)d_in[1];
    const float* b1 = (const float*)d_in[2];
    const float* W2 = (const float*)d_in[3];
    const float* b2 = (const float*)d_in[4];
    float* out      = (float*)d_out;
    float* partial  = (float*)d_ws;                  // 2048 floats

    const int B = in_sizes[0] / (L * L);             // 16

    site_kernel<<<B * BLOCKS_PER_B, THREADS, 0, stream>>>(x, W1, b1, W2, partial);
    reduce_kernel<<<B, 128, 0, stream>>>(partial, W2, b2, out);
}

// Round 11
// 32.342 us; speedup vs baseline: 2.5335x; 1.0197x over previous
//
#include <hip/hip_runtime.h>

#define L 512
#define LMASK 511
#define HID 32

constexpr int THREADS        = 256;
constexpr int ROWS_PER_BLOCK = 4;
constexpr int BLOCKS_PER_B   = L / ROWS_PER_BLOCK;   // 128
constexpr int NTAB           = 2048;                 // cells of 1/64 z', z' in [-16,16]
constexpr int GT             = 5;                    // table groups (20 h)
constexpr int NPAIR_E        = 6;                    // exp pairs (12 h)

// Magic addressing: mantissa of (256*z' + 4098 + 2^23) = byte offset into table
constexpr float MAGIC   = 8388608.0f;                // 2^23
constexpr float CLAMPLO = 8388608.0f;                // cell 0
constexpr float CLAMPHI = 8396796.0f;                // 2^23 + 4*2047

// Fused: per-block prep + table build + stencil + hybrid table/exp2 MLP.
// R11: fine-grained straight-line interleave of table groups and exp pairs
// (one basic block) so exp-pair VALU/trans work fills every gather-latency
// window and LDS + issue-port demand stay concurrently saturated.
__global__ __launch_bounds__(THREADS)
void site_kernel(const float* __restrict__ x,
                 const float* __restrict__ W1,
                 const float* __restrict__ b1,
                 const float* __restrict__ W2,
                 float* __restrict__ partial) {
    __shared__ __align__(16) float tab_s[NTAB];      // T(z')=1/(1+2^z'), nearest
    __shared__ __align__(16) float zw_s[GT * 16];    // table groups {wa4 wb4 wc4 w04}
    __shared__ __align__(16) float w2t_s[GT * 4];    // table-path w2
    __shared__ __align__(16) float ew_s[NPAIR_E * 8];// exp pairs {wa01 wb01 wc01 w001}
    __shared__ __align__(8)  float ew2_s[NPAIR_E * 2];

    const int t = threadIdx.x;
    const float Ke = 2.8853900817779268f;            // 2*log2(e)

    if (t < HID) {
        if (t < 4 * GT) {                            // table-path h
            const float K256 = 256.0f * Ke;
            const int g = t >> 2, q = t & 3;
            zw_s[g * 16 +  0 + q] = K256 * W1[t * 3 + 0];
            zw_s[g * 16 +  4 + q] = K256 * W1[t * 3 + 1];
            zw_s[g * 16 +  8 + q] = K256 * W1[t * 3 + 2];
            zw_s[g * 16 + 12 + q] = fmaf(K256, b1[t], 4098.0f + MAGIC);
            w2t_s[t] = -2.0f * W2[t];                // tanh = 1 - 2*T
        } else {                                     // exp-path h
            const int e = t - 4 * GT, p = e >> 1, q = e & 1;
            ew_s[p * 8 + 0 + q] = Ke * W1[t * 3 + 0];
            ew_s[p * 8 + 2 + q] = Ke * W1[t * 3 + 1];
            ew_s[p * 8 + 4 + q] = Ke * W1[t * 3 + 2];
            ew_s[p * 8 + 6 + q] = Ke * b1[t];
            ew2_s[p * 2 + q]    = -2.0f * W2[t];
        }
    }
    // Table entry i: T at the true center of cell i (magic mapping).
    for (int i = t; i < NTAB; i += THREADS) {
        const float zp = fmaf((float)i, 0.015625f, -16.001953125f);
        tab_s[i] = __builtin_amdgcn_rcpf(1.0f + __builtin_amdgcn_exp2f(zp));
    }
    __syncthreads();

    const int blk = blockIdx.x;
    const int b   = blk >> 7;                        // / BLOCKS_PER_B
    const int i0  = (blk & (BLOCKS_PER_B - 1)) * ROWS_PER_BLOCK;
    const float* __restrict__ xb = x + (size_t)b * (L * L);

    // Features for 8 sites: rows i0..i0+3, cols t and t+256.
    float F0[8], F1[8], F2[8];
#pragma unroll
    for (int g = 0; g < 2; ++g) {
        const int j  = t + g * THREADS;
        const int jm = (j + LMASK) & LMASK, jp = (j + 1) & LMASK;

        float cc[6];                                 // center col, rows i0-1..i0+4
#pragma unroll
        for (int r = 0; r < 6; ++r) {
            const int i = (i0 + r - 1 + L) & LMASK;
            cc[r] = xb[i * L + j];
        }
#pragma unroll
        for (int s = 0; s < 4; ++s) {
            const int i   = i0 + s;
            const float lf = xb[i * L + jm];
            const float rg = xb[i * L + jp];
            const float c  = cc[s + 1];
            const float lr = lf + rg;                // == sx
            const float x1 = lr + cc[s] + cc[s + 2];
            const int k = g * 4 + s;
            F0[k] = c * c;  F1[k] = x1 * c;  F2[k] = lr * c;
        }
    }

    float acc[8] = {0.f, 0.f, 0.f, 0.f, 0.f, 0.f, 0.f, 0.f};
    const char* __restrict__ tb = (const char*)tab_s;

    // One table group (4 h x 8 sites): LDS-gather pipe.
    auto tgroup = [&](const int gq) {
        const float4 wa  = *(const float4*)&zw_s[gq * 16 + 0];
        const float4 wb  = *(const float4*)&zw_s[gq * 16 + 4];
        const float4 wc  = *(const float4*)&zw_s[gq * 16 + 8];
        const float4 w0  = *(const float4*)&zw_s[gq * 16 + 12];
        const float4 w2v = *(const float4*)&w2t_s[gq * 4];
#pragma unroll
        for (int q = 0; q < 4; ++q) {
            const float waq = ((const float*)&wa)[q];
            const float wbq = ((const float*)&wb)[q];
            const float wcq = ((const float*)&wc)[q];
            const float w0q = ((const float*)&w0)[q];
            const float w2q = ((const float*)&w2v)[q];
#pragma unroll
            for (int s = 0; s < 8; ++s) {
                const float uu = fmaf(F0[s], waq, fmaf(F1[s], wbq, fmaf(F2[s], wcq, w0q)));
                const float uc = __builtin_amdgcn_fmed3f(uu, CLAMPLO, CLAMPHI);
                const int  off = __float_as_int(uc) & 0x007FFFFC;
                const float y  = *reinterpret_cast<const float*>(tb + off);
                acc[s] = fmaf(w2q, y, acc[s]);
            }
        }
    };
    // One exp pair (2 h x 8 sites): VALU + trans issue-port work.
    auto epair = [&](const int p) {
        const float4 e0 = *(const float4*)&ew_s[p * 8 + 0];  // wa0 wa1 wb0 wb1
        const float4 e1 = *(const float4*)&ew_s[p * 8 + 4];  // wc0 wc1 w00 w01
        const float2 w2p = *(const float2*)&ew2_s[p * 2];
        const float wa0 = e0.x, wa1 = e0.y, wb0 = e0.z, wb1 = e0.w;
        const float wc0 = e1.x, wc1 = e1.y, w00 = e1.z, w01 = e1.w;
#pragma unroll
        for (int s = 0; s < 8; ++s) {
            float z0 = fmaf(F0[s], wa0, fmaf(F1[s], wb0, fmaf(F2[s], wc0, w00)));
            float z1 = fmaf(F0[s], wa1, fmaf(F1[s], wb1, fmaf(F2[s], wc1, w01)));
            z0 = __builtin_amdgcn_fmed3f(z0, -30.0f, 30.0f);
            z1 = __builtin_amdgcn_fmed3f(z1, -30.0f, 30.0f);
            const float d0 = 1.0f + __builtin_amdgcn_exp2f(z0);
            const float d1 = 1.0f + __builtin_amdgcn_exp2f(z1);
            const float nm = fmaf(w2p.x, d1, w2p.y * d0); // w2a/d0+w2b/d1
            const float rr = __builtin_amdgcn_rcpf(d0 * d1);
            acc[s] = fmaf(nm, rr, acc[s]);
        }
    };

    // Fine interleave, single basic block: gather latency hides under exp work.
    tgroup(0); epair(0);
    tgroup(1); epair(1);
    tgroup(2); epair(2);
    tgroup(3); epair(3);
    tgroup(4); epair(4); epair(5);

    float a = ((acc[0] + acc[1]) + (acc[2] + acc[3]))
            + ((acc[4] + acc[5]) + (acc[6] + acc[7]));
#pragma unroll
    for (int off = 32; off > 0; off >>= 1)
        a += __shfl_down(a, off, 64);

    __shared__ float wsum[THREADS / 64];
    const int wid = t >> 6, lane = t & 63;
    if (lane == 0) wsum[wid] = a;
    __syncthreads();
    if (t == 0)
        partial[blk] = (wsum[0] + wsum[1]) + (wsum[2] + wsum[3]);
}

// Deterministic fixed-order reduction + folded tanh constant.
__global__ __launch_bounds__(128)
void reduce_kernel(const float* __restrict__ partial,
                   const float* __restrict__ W2,
                   const float* __restrict__ b2,
                   float* __restrict__ out) {
    const int b = blockIdx.x, t = threadIdx.x;
    const float NS = (float)(L * L);                 // 262144 sites per config

    float v = partial[b * BLOCKS_PER_B + t];
    if (t < HID) v += NS * W2[t];                    // + L^2 * sum_h W2[h]
    if (t == 0)  v += NS * b2[0];                    // + L^2 * b2

#pragma unroll
    for (int off = 32; off > 0; off >>= 1)
        v += __shfl_down(v, off, 64);

    __shared__ float ws2[2];
    if ((t & 63) == 0) ws2[t >> 6] = v;
    __syncthreads();
    if (t == 0) out[b] = ws2[0] + ws2[1];
}

extern "C" void kernel_launch(void* const* d_in, const int* in_sizes, int n_in,
                              void* d_out, int out_size, void* d_ws, size_t ws_size,
                              hipStream_t stream) {
    const float* x  = (const float*)d_in[0];
    const float* W1 = (const float*)d_in[1];
    const float* b1 = (const float*)d_in[2];
    const float* W2 = (const float*)d_in[3];
    const float* b2 = (const float*)d_in[4];
    float* out      = (float*)d_out;
    float* partial  = (float*)d_ws;                  // 2048 floats

    const int B = in_sizes[0] / (L * L);             // 16

    site_kernel<<<B * BLOCKS_PER_B, THREADS, 0, stream>>>(x, W1, b1, W2, partial);
    reduce_kernel<<<B, 128, 0, stream>>>(partial, W2, b2, out);
}